// Round 6
// baseline (1827.956 us; speedup 1.0000x reference)
//
#include <hip/hip_runtime.h>
#include <hip/hip_bf16.h>

// ECLGCNN: ChebConv(K=3) on 49152 disjoint 32-node graphs -> per-sample BN ->
// sigmoid -> LSTM(48 steps, H=512) -> linear head. Inputs fp32, output fp32.
// R6: LSTM as ONE persistent kernel (256 blocks = 1/CU, co-resident via 149KB
// LDS). W'-slice resident in LDS for all 48 steps, c in registers, A streamed
// via global_load_lds dbuf, device-scope grid barrier between steps.

#define B_    1024
#define T_    48
#define NPG_  32
#define F_    5
#define H_    512
#define EPG_  256
#define NG_   (B_*T_)          // 49152 graphs
#define N_    (B_*T_*NPG_)     // 1572864 nodes
#define E_    (B_*T_*EPG_)     // 12582912 edges
#define NF_   (N_*F_)          // 7864320

typedef __bf16 bf16x8 __attribute__((ext_vector_type(8)));
typedef float  f32x4  __attribute__((ext_vector_type(4)));
typedef __hip_bfloat16 bf16;

__device__ __forceinline__ float sigm(float x)   { return 1.0f/(1.0f+__expf(-x)); }
__device__ __forceinline__ float tanh_f(float x) { return 2.0f/(1.0f+__expf(-2.0f*x)) - 1.0f; }

__device__ __forceinline__ void gl_lds16(const void* g, void* l) {
    __builtin_amdgcn_global_load_lds((const __attribute__((address_space(1))) unsigned int*)g,
                                     (__attribute__((address_space(3))) unsigned int*)l, 16, 0, 0);
}

__global__ __launch_bounds__(256) void k_zero(float4* p, int n) {
    int i = blockIdx.x*256 + threadIdx.x;
    if (i < n) p[i] = make_float4(0.f, 0.f, 0.f, 0.f);
}

// Pack W' = [Wih | Whh] row-major [2048][672], fp32 -> bf16.
__global__ __launch_bounds__(256) void k_pack(const float* __restrict__ Wih,
                                              const float* __restrict__ Whh,
                                              bf16* __restrict__ Wp) {
    int i = blockIdx.x*256 + threadIdx.x;           // < 2048*672
    int r = i / 672, c = i - r*672;
    float v = (c < 160) ? Wih[r*160 + c] : Whh[r*512 + (c-160)];
    Wp[i] = __float2bfloat16(v);
}

// Graph-per-wave ChebConv: 4 graphs per 256-thread block (unchanged from R5).
__global__ __launch_bounds__(256) void k_graph(
    const float* __restrict__ x, const float* __restrict__ ea,
    const float* __restrict__ cW, const float* __restrict__ cb,
    const int* __restrict__ ei, float* __restrict__ y_pre,
    float* __restrict__ part)
{
    const int tid = threadIdx.x, w = tid >> 6, lane = tid & 63;
    const int g = blockIdx.x*4 + w;
    __shared__ float Msh[4][1056];
    __shared__ float dinv[4][32];
    __shared__ float T0s[4][160], T1s[4][160], S0s[4][160], T2s[4][160];
    __shared__ float Wsh[75], bsh[5];
    float* mt = Msh[w];

    if (lane < 75) Wsh[lane] = cW[lane];
    if (lane < 5)  bsh[lane] = cb[lane];
    const float4 ew = *reinterpret_cast<const float4*>(ea + (size_t)g*256 + lane*4);
    const int4   es = *reinterpret_cast<const int4*>(ei + (size_t)g*256 + lane*4);
    const int4   ed = *reinterpret_cast<const int4*>(ei + (size_t)E_ + (size_t)g*256 + lane*4);
    T0s[w][lane]      = x[(size_t)g*160 + lane];
    T0s[w][64+lane]   = x[(size_t)g*160 + 64 + lane];
    if (lane < 32) T0s[w][128+lane] = x[(size_t)g*160 + 128 + lane];
    for (int i = lane; i < 1056; i += 64) mt[i] = 0.f;
    __syncthreads();
    atomicAdd(&mt[(ed.x & 31)*33 + (es.x & 31)], ew.x);
    atomicAdd(&mt[(ed.y & 31)*33 + (es.y & 31)], ew.y);
    atomicAdd(&mt[(ed.z & 31)*33 + (es.z & 31)], ew.z);
    atomicAdd(&mt[(ed.w & 31)*33 + (es.w & 31)], ew.w);
    __syncthreads();
    if (lane < 32) {
        float dg = 0.f;
        #pragma unroll
        for (int d = 0; d < 32; ++d) dg += mt[d*33 + lane];
        dinv[w][lane] = dg > 0.f ? rsqrtf(dg) : 0.f;
    }
    __syncthreads();
    for (int i = lane; i < 160; i += 64) S0s[w][i] = dinv[w][i/5] * T0s[w][i];
    __syncthreads();
    for (int i = lane; i < 160; i += 64) {
        const int d = i/5, f = i - 5*d;
        float a = 0.f;
        #pragma unroll 8
        for (int s = 0; s < 32; ++s) a += mt[d*33+s] * S0s[w][s*5+f];
        T1s[w][i] = -dinv[w][d]*a;
    }
    __syncthreads();
    for (int i = lane; i < 160; i += 64) S0s[w][i] = dinv[w][i/5] * T1s[w][i];
    __syncthreads();
    for (int i = lane; i < 160; i += 64) {
        const int d = i/5, f = i - 5*d;
        float a = 0.f;
        #pragma unroll 8
        for (int s = 0; s < 32; ++s) a += mt[d*33+s] * S0s[w][s*5+f];
        T2s[w][i] = -2.f*dinv[w][d]*a - T0s[w][i];
    }
    __syncthreads();
    float* vb = mt;
    for (int i = lane; i < 160; i += 64) {
        const int n = i/5, f = i - 5*n;
        float v = bsh[f];
        #pragma unroll
        for (int c = 0; c < 5; ++c)
            v += T0s[w][n*5+c]*Wsh[c*5+f] + T1s[w][n*5+c]*Wsh[25+c*5+f] + T2s[w][n*5+c]*Wsh[50+c*5+f];
        y_pre[(size_t)g*160 + i] = v;
        vb[i] = v;
    }
    __syncthreads();
    if (lane < 10) {
        const int f = lane % 5; const bool sq = lane >= 5;
        float sm = 0.f;
        #pragma unroll 8
        for (int n = 0; n < 32; ++n) { float v = vb[n*5+f]; sm += sq ? v*v : v; }
        part[(size_t)g*10 + lane] = sm;
    }
}

__global__ __launch_bounds__(64) void k_stats(const float* __restrict__ part,
                                              float* __restrict__ bn_acc) {
    const int b = blockIdx.x, tid = threadIdx.x;
    if (tid < 10) {
        float s = 0.f;
        for (int j = 0; j < T_; ++j) s += part[((size_t)b*T_ + j)*10 + tid];
        bn_acc[b*10 + tid] = s;
    }
}

__global__ __launch_bounds__(256) void k_bn(
    const float* __restrict__ y_pre, const float* __restrict__ bn_acc,
    const float* __restrict__ gamma, const float* __restrict__ beta,
    bf16* __restrict__ X)
{
    const int i = blockIdx.x*256 + threadIdx.x;
    const int b   = i / 7680;
    const int rem = i - b*7680;
    const int t   = rem / 160;
    const int pf  = rem - t*160;
    const int f   = pf % 5;
    const float inv  = 1.0f/1536.0f;
    const float mean = bn_acc[b*10+f]*inv;
    const float var  = bn_acc[b*10+5+f]*inv - mean*mean;
    const float v = gamma[f]*(y_pre[i]-mean)*rsqrtf(var+1e-5f) + beta[f];
    X[((size_t)t*B_ + b)*160 + pf] = __float2bfloat16(sigm(v));
}

// ---------------- persistent LSTM ----------------
// grid (8,32) = 256 blocks (1/CU), 512 thr (8 waves). Block = 128 m-rows x
// (16 units x 4 gates). Dynamic LDS: W-slice 64x672 bf16 @1360B stride (85
// granules, conflict-free b128 since 5*lo distinct mod 8) + two 32KB A bufs.
// Chunks/step: X 96k + 64k, h 4x128k; xor slot<->granule swizzle.
// One device-scope grid barrier per step (h ping-pong).
#define WB  87040
#define BUF0 87040
#define BUF1 119808
#define SMEM_SZ 152576

__device__ __forceinline__ void stage_chunk(const char* base, int strideB, int gpr,
                                            int xmask, int npass, char* buf, int tid) {
    for (int p = 0; p < npass; ++p) {
        const int g = p*512 + tid;
        const int row = g / gpr;
        const int sl  = g - row*gpr;
        const int kp  = sl ^ (row & xmask);
        gl_lds16(base + (size_t)row*strideB + kp*16, buf + g*16);
    }
}

__device__ __forceinline__ void mfma_chunk(const char* buf, const char* wl, int gpr,
                                           int xmask, int nks, int kg, int arow,
                                           int lo, int quad, f32x4 acc[4]) {
    for (int ks = 0; ks < nks; ++ks) {
        const int ag = ks*4 + quad;
        const bf16x8 a = *reinterpret_cast<const bf16x8*>(
            buf + ((size_t)arow*gpr + (ag ^ (arow & xmask)))*16);
        #pragma unroll
        for (int g = 0; g < 4; ++g) {
            const bf16x8 b = *reinterpret_cast<const bf16x8*>(
                wl + (size_t)(g*16 + lo)*1360 + (kg + ks*4 + quad)*16);
            acc[g] = __builtin_amdgcn_mfma_f32_16x16x32_bf16(a, b, acc[g], 0, 0, 0);
        }
    }
}

__global__ __launch_bounds__(512, 2) void k_lstm(
    const bf16* __restrict__ X, const bf16* __restrict__ Wp,
    const float* __restrict__ bih, const float* __restrict__ bhh,
    bf16* __restrict__ hA, bf16* __restrict__ hB,
    bf16* __restrict__ hs, unsigned int* __restrict__ ctr)
{
    extern __shared__ char sm[];
    char* wl = sm;
    char* b0 = sm + BUF0;
    char* b1 = sm + BUF1;
    const int tid = threadIdx.x;
    const int lane = tid & 63, w = tid >> 6;
    const int lo = lane & 15, quad = lane >> 4;
    const int m0 = blockIdx.x*128;
    const int u0 = blockIdx.y*16;
    const int arow = w*16 + lo;

    // W-slice preload: 64 rows x 84 granules -> LDS @ stride 1360B
    for (int p = 0; p < 11; ++p) {
        const int idx = p*512 + tid;
        if (idx < 5376) {
            const int wr = idx / 84, gk = idx - wr*84;
            const int grow = ((wr >> 4) << 9) + u0 + (wr & 15);
            const bf16x8 v = *reinterpret_cast<const bf16x8*>(Wp + (size_t)grow*672 + gk*8);
            *reinterpret_cast<bf16x8*>(wl + (size_t)wr*1360 + gk*16) = v;
        }
    }
    const int u = u0 + lo;
    const float bI = bih[u]      + bhh[u];
    const float bF = bih[512+u]  + bhh[512+u];
    const float bG = bih[1024+u] + bhh[1024+u];
    const float bO = bih[1536+u] + bhh[1536+u];
    float c_reg[4] = {0.f, 0.f, 0.f, 0.f};

    for (int t = 0; t < T_; ++t) {
        f32x4 acc[4] = {};
        const char* Xt = (const char*)X + (size_t)t*327680 + (size_t)m0*320;
        stage_chunk(Xt, 320, 12, 3, 3, b0, tid);          // X k[0:96)
        __syncthreads();
        stage_chunk(Xt + 192, 320, 8, 7, 2, b1, tid);     // X k[96:160)
        mfma_chunk(b0, wl, 12, 3, 3, 0, arow, lo, quad, acc);
        __syncthreads();
        if (t > 0) {
            const char* hb = (const char*)((t & 1) ? hA : hB) + (size_t)m0*1024;
            stage_chunk(hb,       1024, 16, 7, 4, b0, tid);
            mfma_chunk(b1, wl, 8, 7, 2, 12, arow, lo, quad, acc);
            __syncthreads();
            stage_chunk(hb + 256, 1024, 16, 7, 4, b1, tid);
            mfma_chunk(b0, wl, 16, 7, 4, 20, arow, lo, quad, acc);
            __syncthreads();
            stage_chunk(hb + 512, 1024, 16, 7, 4, b0, tid);
            mfma_chunk(b1, wl, 16, 7, 4, 36, arow, lo, quad, acc);
            __syncthreads();
            stage_chunk(hb + 768, 1024, 16, 7, 4, b1, tid);
            mfma_chunk(b0, wl, 16, 7, 4, 52, arow, lo, quad, acc);
            __syncthreads();
            mfma_chunk(b1, wl, 16, 7, 4, 68, arow, lo, quad, acc);
        } else {
            mfma_chunk(b1, wl, 8, 7, 2, 12, arow, lo, quad, acc);
        }
        // epilogue: fused LSTM pointwise; c lives in registers across steps
        bf16* hcur = (t & 1) ? hB : hA;
        bf16* hst  = hs + (size_t)t*524288;
        #pragma unroll
        for (int r = 0; r < 4; ++r) {
            const int m = m0 + w*16 + quad*4 + r;
            const int idx = m*512 + u;
            const float iv = acc[0][r] + bI;
            const float fv = acc[1][r] + bF;
            const float gv = acc[2][r] + bG;
            const float ov = acc[3][r] + bO;
            const float c_new = sigm(fv)*c_reg[r] + sigm(iv)*tanh_f(gv);
            c_reg[r] = c_new;
            const float hn = sigm(ov)*tanh_f(c_new);
            hcur[idx] = __float2bfloat16(hn);
            hst[idx]  = __float2bfloat16(sigm(hn));
        }
        __syncthreads();                                   // all stores drained (per-wave vmcnt)
        if (t < T_-1) {
            if (tid == 0) {
                __threadfence();                           // release: writeback to device scope
                __hip_atomic_fetch_add(ctr, 1u, __ATOMIC_RELEASE, __HIP_MEMORY_SCOPE_AGENT);
                const unsigned target = 256u*(t+1);
                while (__hip_atomic_load(ctr, __ATOMIC_ACQUIRE, __HIP_MEMORY_SCOPE_AGENT) < target)
                    __builtin_amdgcn_s_sleep(2);
                __threadfence();                           // acquire: invalidate stale lines
            }
            __syncthreads();
        }
    }
}

// out[b,j] = sigmoid( sum_{t,u} sig_h[t,b,u] * lin_W[j, t*512+u] + lin_b[j] )
__global__ __launch_bounds__(256) void k_final(
    const bf16* __restrict__ hs, const float* __restrict__ lW,
    const float* __restrict__ lb, float* __restrict__ out)
{
    const int b = blockIdx.x, tid = threadIdx.x;
    const int u = tid*2;
    float a0=0.f, a1=0.f, a2=0.f, a3=0.f;
    for (int t = 0; t < T_; ++t) {
        const bf16* hr = hs + ((size_t)t*B_ + b)*H_ + u;
        const float h0 = (float)hr[0], h1 = (float)hr[1];
        const int o = t*H_ + u;
        a0 += h0*lW[o]         + h1*lW[o+1];
        a1 += h0*lW[24576+o]   + h1*lW[24576+o+1];
        a2 += h0*lW[49152+o]   + h1*lW[49152+o+1];
        a3 += h0*lW[73728+o]   + h1*lW[73728+o+1];
    }
    #pragma unroll
    for (int off = 32; off > 0; off >>= 1) {
        a0 += __shfl_down(a0, off, 64);
        a1 += __shfl_down(a1, off, 64);
        a2 += __shfl_down(a2, off, 64);
        a3 += __shfl_down(a3, off, 64);
    }
    __shared__ float red[4][4];
    const int wave = tid >> 6, lane = tid & 63;
    if (lane == 0) { red[0][wave]=a0; red[1][wave]=a1; red[2][wave]=a2; red[3][wave]=a3; }
    __syncthreads();
    if (tid < 4) {
        float s = red[tid][0]+red[tid][1]+red[tid][2]+red[tid][3] + lb[tid];
        out[b*4 + tid] = sigm(s);
    }
}

extern "C" void kernel_launch(void* const* d_in, const int* in_sizes, int n_in,
                              void* d_out, int out_size, void* d_ws, size_t ws_size,
                              hipStream_t stream) {
    const float* x   = (const float*)d_in[0];
    const float* ea  = (const float*)d_in[1];
    const float* cW  = (const float*)d_in[2];
    const float* cb  = (const float*)d_in[3];
    const float* gam = (const float*)d_in[4];
    const float* bet = (const float*)d_in[5];
    const float* Wih = (const float*)d_in[6];
    const float* Whh = (const float*)d_in[7];
    const float* bih = (const float*)d_in[8];
    const float* bhh = (const float*)d_in[9];
    const float* lW  = (const float*)d_in[10];
    const float* lb  = (const float*)d_in[11];
    const int*   ei  = (const int*)d_in[12];
    float* out = (float*)d_out;

    // Workspace (73.0 MB):
    // [bn_acc 40KB][Wp 2.75MB][X 15.7MB][big 54.5MB]
    // big phase 1: y_pre @0 (31.5MB), part @32MB (1.97MB)
    // big phase 2: ctr @0, hA @2MB, hB @3MB, hs @4MB (50.3MB)
    char* ws = (char*)d_ws;
    float* bn_acc = (float*)ws;
    bf16*  Wp     = (bf16*)(ws + 40960);
    bf16*  X      = (bf16*)(ws + 2793472);
    char*  big    = ws + 18522112;
    float* y_pre  = (float*)big;
    float* part   = (float*)(big + 33554432);
    unsigned int* ctr = (unsigned int*)big;            // after y_pre is dead
    bf16*  hA     = (bf16*)(big + 2097152);
    bf16*  hB     = (bf16*)(big + 3145728);
    bf16*  hs     = (bf16*)(big + 4194304);

    (void)hipFuncSetAttribute((const void*)k_lstm,
                              hipFuncAttributeMaxDynamicSharedMemorySize, SMEM_SZ);

    k_pack<<<5376, 256, 0, stream>>>(Wih, Whh, Wp);
    k_graph<<<NG_/4, 256, 0, stream>>>(x, ea, cW, cb, ei, y_pre, part);
    k_stats<<<B_, 64, 0, stream>>>(part, bn_acc);
    k_bn<<<NF_/256, 256, 0, stream>>>(y_pre, bn_acc, gam, bet, X);
    k_zero<<<1, 256, 0, stream>>>((float4*)ctr, 1);    // zero grid-barrier counter
    k_lstm<<<dim3(8, 32), 512, SMEM_SZ, stream>>>(X, Wp, bih, bhh, hA, hB, hs, ctr);
    k_final<<<B_, 256, 0, stream>>>(hs, lW, lb, out);
}

// Round 7
// 783.695 us; speedup vs baseline: 2.3325x; 2.3325x over previous
//
#include <hip/hip_runtime.h>
#include <hip/hip_bf16.h>

// ECLGCNN: ChebConv(K=3) on 49152 disjoint 32-node graphs -> per-sample BN ->
// sigmoid -> LSTM(48 steps, H=512) -> linear head. Inputs fp32, output fp32.
// R7: revert persistent LSTM (1 block/CU = no latency hiding). Per-step kernel
// with 3 staged K-phases (6 barriers/step vs R5's 42), 64KB dynamic LDS,
// 2 blocks/CU. k_graph T-loops restructured to broadcast reads (LDS-issue cut).

#define B_    1024
#define T_    48
#define NPG_  32
#define F_    5
#define H_    512
#define EPG_  256
#define NG_   (B_*T_)          // 49152 graphs
#define N_    (B_*T_*NPG_)     // 1572864 nodes
#define E_    (B_*T_*EPG_)     // 12582912 edges
#define NF_   (N_*F_)          // 7864320

typedef __bf16 bf16x8 __attribute__((ext_vector_type(8)));
typedef float  f32x4  __attribute__((ext_vector_type(4)));
typedef __hip_bfloat16 bf16;

__device__ __forceinline__ float sigm(float x)   { return 1.0f/(1.0f+__expf(-x)); }
__device__ __forceinline__ float tanh_f(float x) { return 2.0f/(1.0f+__expf(-2.0f*x)) - 1.0f; }

__device__ __forceinline__ void gl_lds16(const void* g, void* l) {
    __builtin_amdgcn_global_load_lds((const __attribute__((address_space(1))) unsigned int*)g,
                                     (__attribute__((address_space(3))) unsigned int*)l, 16, 0, 0);
}

__global__ __launch_bounds__(256) void k_zero(float4* p, int n) {
    int i = blockIdx.x*256 + threadIdx.x;
    if (i < n) p[i] = make_float4(0.f, 0.f, 0.f, 0.f);
}

// Pack W' = [Wih | Whh] row-major [2048][672], fp32 -> bf16.
__global__ __launch_bounds__(256) void k_pack(const float* __restrict__ Wih,
                                              const float* __restrict__ Whh,
                                              bf16* __restrict__ Wp) {
    int i = blockIdx.x*256 + threadIdx.x;           // < 2048*672
    int r = i / 672, c = i - r*672;
    float v = (c < 160) ? Wih[r*160 + c] : Whh[r*512 + (c-160)];
    Wp[i] = __float2bfloat16(v);
}

// Graph-per-wave ChebConv: 4 graphs per 256-thread block.
// T-loops: lane = output node d; M-row read conflict-free (stride 33), S rows
// padded to 8 floats -> float4+float broadcast reads (3 LDS insts / 5 MACs).
__global__ __launch_bounds__(256) void k_graph(
    const float* __restrict__ x, const float* __restrict__ ea,
    const float* __restrict__ cW, const float* __restrict__ cb,
    const int* __restrict__ ei, float* __restrict__ y_pre,
    float* __restrict__ part)
{
    const int tid = threadIdx.x, w = tid >> 6, lane = tid & 63;
    const int g = blockIdx.x*4 + w;
    __shared__ float Msh[4][1056];                  // Mt[d][s], row stride 33
    __shared__ float dinv[4][32];
    __shared__ float T0s[4][160], T1s[4][160], T2s[4][160];
    __shared__ __align__(16) float Spad[4][256];    // scaled vec, rows padded to 8
    __shared__ float Wsh[75], bsh[5];
    float* mt = Msh[w];

    if (lane < 75) Wsh[lane] = cW[lane];
    if (lane < 5)  bsh[lane] = cb[lane];
    const float4 ew = *reinterpret_cast<const float4*>(ea + (size_t)g*256 + lane*4);
    const int4   es = *reinterpret_cast<const int4*>(ei + (size_t)g*256 + lane*4);
    const int4   ed = *reinterpret_cast<const int4*>(ei + (size_t)E_ + (size_t)g*256 + lane*4);
    T0s[w][lane]      = x[(size_t)g*160 + lane];
    T0s[w][64+lane]   = x[(size_t)g*160 + 64 + lane];
    if (lane < 32) T0s[w][128+lane] = x[(size_t)g*160 + 128 + lane];
    for (int i = lane; i < 1056; i += 64) mt[i] = 0.f;
    __syncthreads();
    atomicAdd(&mt[(ed.x & 31)*33 + (es.x & 31)], ew.x);
    atomicAdd(&mt[(ed.y & 31)*33 + (es.y & 31)], ew.y);
    atomicAdd(&mt[(ed.z & 31)*33 + (es.z & 31)], ew.z);
    atomicAdd(&mt[(ed.w & 31)*33 + (es.w & 31)], ew.w);
    __syncthreads();
    if (lane < 32) {                                // deg[s] = sum_d Mt[d][s]
        float dg = 0.f;
        #pragma unroll
        for (int d = 0; d < 32; ++d) dg += mt[d*33 + lane];
        dinv[w][lane] = dg > 0.f ? rsqrtf(dg) : 0.f;
    }
    __syncthreads();
    for (int i = lane; i < 160; i += 64) Spad[w][(i/5)*8 + (i%5)] = dinv[w][i/5]*T0s[w][i];
    __syncthreads();
    if (lane < 32) {                                // T1 = -dinv .* (Mt @ S0)
        const int d = lane;
        float a0=0.f,a1=0.f,a2=0.f,a3=0.f,a4=0.f;
        #pragma unroll 4
        for (int s = 0; s < 32; ++s) {
            const float m = mt[d*33+s];
            const float4 sv = *reinterpret_cast<const float4*>(&Spad[w][s*8]);
            const float s4 = Spad[w][s*8+4];
            a0 += m*sv.x; a1 += m*sv.y; a2 += m*sv.z; a3 += m*sv.w; a4 += m*s4;
        }
        const float sc = -dinv[w][d];
        T1s[w][d*5+0]=sc*a0; T1s[w][d*5+1]=sc*a1; T1s[w][d*5+2]=sc*a2;
        T1s[w][d*5+3]=sc*a3; T1s[w][d*5+4]=sc*a4;
    }
    __syncthreads();
    for (int i = lane; i < 160; i += 64) Spad[w][(i/5)*8 + (i%5)] = dinv[w][i/5]*T1s[w][i];
    __syncthreads();
    if (lane < 32) {                                // T2 = 2 L~ T1 - T0
        const int d = lane;
        float a0=0.f,a1=0.f,a2=0.f,a3=0.f,a4=0.f;
        #pragma unroll 4
        for (int s = 0; s < 32; ++s) {
            const float m = mt[d*33+s];
            const float4 sv = *reinterpret_cast<const float4*>(&Spad[w][s*8]);
            const float s4 = Spad[w][s*8+4];
            a0 += m*sv.x; a1 += m*sv.y; a2 += m*sv.z; a3 += m*sv.w; a4 += m*s4;
        }
        const float sc = -2.f*dinv[w][d];
        T2s[w][d*5+0]=sc*a0-T0s[w][d*5+0]; T2s[w][d*5+1]=sc*a1-T0s[w][d*5+1];
        T2s[w][d*5+2]=sc*a2-T0s[w][d*5+2]; T2s[w][d*5+3]=sc*a3-T0s[w][d*5+3];
        T2s[w][d*5+4]=sc*a4-T0s[w][d*5+4];
    }
    __syncthreads();
    float* vb = mt;                                 // reuse adjacency LDS for y
    for (int i = lane; i < 160; i += 64) {
        const int n = i/5, f = i - 5*n;
        float v = bsh[f];
        #pragma unroll
        for (int c = 0; c < 5; ++c)
            v += T0s[w][n*5+c]*Wsh[c*5+f] + T1s[w][n*5+c]*Wsh[25+c*5+f] + T2s[w][n*5+c]*Wsh[50+c*5+f];
        y_pre[(size_t)g*160 + i] = v;
        vb[i] = v;
    }
    __syncthreads();
    if (lane < 10) {                                // per-graph BN partials
        const int f = lane % 5; const bool sq = lane >= 5;
        float sm = 0.f;
        #pragma unroll 8
        for (int n = 0; n < 32; ++n) { float v = vb[n*5+f]; sm += sq ? v*v : v; }
        part[(size_t)g*10 + lane] = sm;
    }
}

__global__ __launch_bounds__(64) void k_stats(const float* __restrict__ part,
                                              float* __restrict__ bn_acc) {
    const int b = blockIdx.x, tid = threadIdx.x;
    if (tid < 10) {
        float s = 0.f;
        for (int j = 0; j < T_; ++j) s += part[((size_t)b*T_ + j)*10 + tid];
        bn_acc[b*10 + tid] = s;
    }
}

__global__ __launch_bounds__(256) void k_bn(
    const float* __restrict__ y_pre, const float* __restrict__ bn_acc,
    const float* __restrict__ gamma, const float* __restrict__ beta,
    bf16* __restrict__ X)
{
    const int i = blockIdx.x*256 + threadIdx.x;
    const int b   = i / 7680;
    const int rem = i - b*7680;
    const int t   = rem / 160;
    const int pf  = rem - t*160;
    const int f   = pf % 5;
    const float inv  = 1.0f/1536.0f;
    const float mean = bn_acc[b*10+f]*inv;
    const float var  = bn_acc[b*10+5+f]*inv - mean*mean;
    const float v = gamma[f]*(y_pre[i]-mean)*rsqrtf(var+1e-5f) + beta[f];
    X[((size_t)t*B_ + b)*160 + pf] = __float2bfloat16(sigm(v));
}

// ---- LSTM step: 3-phase staged GEMM, 6 barriers/step ----
// Grid (16,32)=512 blocks, 256 thr (4 waves), tile 64m x 64n (16u x 4 gates).
// Dynamic LDS 64KB: A[32K] + W[32K], single-buffered across phases.
// Phase 0: X  K=160 (gpr=20 granules/row, xor mask 3)
// Phase 1: h[0:256)   K=256 (gpr=32, mask 7)
// Phase 2: h[256:512) K=256
// Slot S holds global (row=S/gpr, col=(S%gpr)^(row&mask)); frag reads invert.

__device__ __forceinline__ void stage_A(const char* gbase, int strideB, char* lds,
                                        int gpr, int xmask, int nper, int tid) {
    for (int p = 0; p < nper; ++p) {
        const int S = p*256 + tid;
        const int row = S / gpr;
        const int col = (S - row*gpr) ^ (row & xmask);
        gl_lds16(gbase + (size_t)row*strideB + (size_t)col*16, lds + (size_t)S*16);
    }
}

__device__ __forceinline__ void stage_W(const char* Wbase, char* lds,
                                        int gpr, int xmask, int nper, int tid, int u0) {
    for (int p = 0; p < nper; ++p) {
        const int S = p*256 + tid;
        const int row = S / gpr;
        const int col = (S - row*gpr) ^ (row & xmask);
        const int wrow = ((row >> 4) << 9) + u0 + (row & 15);
        gl_lds16(Wbase + (size_t)wrow*1344 + (size_t)col*16, lds + (size_t)S*16);
    }
}

__device__ __forceinline__ void mfma_phase(const char* Al, const char* Wl, int gpr,
                                           int xmask, int nkk, int arow, int lo,
                                           int quad, f32x4 acc[4]) {
    for (int kk = 0; kk < nkk; ++kk) {
        const int kq = kk*4 + quad;
        const bf16x8 a = *reinterpret_cast<const bf16x8*>(
            Al + ((size_t)arow*gpr + (kq ^ (arow & xmask)))*16);
        #pragma unroll
        for (int g = 0; g < 4; ++g) {
            const int wr = g*16 + lo;
            const bf16x8 b = *reinterpret_cast<const bf16x8*>(
                Wl + ((size_t)wr*gpr + (kq ^ (wr & xmask)))*16);
            acc[g] = __builtin_amdgcn_mfma_f32_16x16x32_bf16(a, b, acc[g], 0, 0, 0);
        }
    }
}

__global__ __launch_bounds__(256) void k_step(
    const bf16* __restrict__ Xt,  const bf16* __restrict__ Wp,
    const float* __restrict__ bih, const float* __restrict__ bhh,
    const bf16* __restrict__ h_in, float* __restrict__ c_buf,
    bf16* __restrict__ h_out, bf16* __restrict__ hs_t)
{
    extern __shared__ char sm[];
    char* Al = sm;
    char* Wl = sm + 32768;
    const int tid = threadIdx.x;
    const int lane = tid & 63, w = tid >> 6;
    const int lo = lane & 15, quad = lane >> 4;
    const int m0 = blockIdx.x*64;
    const int u0 = blockIdx.y*16;
    const int arow = w*16 + lo;
    f32x4 acc[4] = {};

    const char* Xb = (const char*)Xt + (size_t)m0*320;
    const char* Hb = (const char*)h_in + (size_t)m0*1024;
    const char* Wb = (const char*)Wp;

    // phase 0: X part (K=160)
    stage_A(Xb, 320, Al, 20, 3, 5, tid);
    stage_W(Wb, Wl, 20, 3, 5, tid, u0);
    const int u = u0 + lo;
    const float bI = bih[u]      + bhh[u];
    const float bF = bih[512+u]  + bhh[512+u];
    const float bG = bih[1024+u] + bhh[1024+u];
    const float bO = bih[1536+u] + bhh[1536+u];
    __syncthreads();                                  // drains vmcnt: LDS ready
    mfma_phase(Al, Wl, 20, 3, 5, arow, lo, quad, acc);
    __syncthreads();
    // phase 1: h[0:256)
    stage_A(Hb, 1024, Al, 32, 7, 8, tid);
    stage_W(Wb + 320, Wl, 32, 7, 8, tid, u0);
    __syncthreads();
    mfma_phase(Al, Wl, 32, 7, 8, arow, lo, quad, acc);
    __syncthreads();
    // phase 2: h[256:512)
    stage_A(Hb + 512, 1024, Al, 32, 7, 8, tid);
    stage_W(Wb + 832, Wl, 32, 7, 8, tid, u0);
    __syncthreads();
    mfma_phase(Al, Wl, 32, 7, 8, arow, lo, quad, acc);

    #pragma unroll
    for (int r = 0; r < 4; ++r) {
        const int m = m0 + w*16 + quad*4 + r;
        const int idx = m*512 + u;
        const float iv = acc[0][r] + bI;
        const float fv = acc[1][r] + bF;
        const float gv = acc[2][r] + bG;
        const float ov = acc[3][r] + bO;
        const float c_new = sigm(fv)*c_buf[idx] + sigm(iv)*tanh_f(gv);
        const float hn    = sigm(ov)*tanh_f(c_new);
        c_buf[idx] = c_new;
        h_out[idx] = __float2bfloat16(hn);
        hs_t[idx]  = __float2bfloat16(sigm(hn));
    }
}

// out[b,j] = sigmoid( sum_{t,u} sig_h[t,b,u] * lin_W[j, t*512+u] + lin_b[j] )
__global__ __launch_bounds__(256) void k_final(
    const bf16* __restrict__ hs, const float* __restrict__ lW,
    const float* __restrict__ lb, float* __restrict__ out)
{
    const int b = blockIdx.x, tid = threadIdx.x;
    const int u = tid*2;
    float a0=0.f, a1=0.f, a2=0.f, a3=0.f;
    for (int t = 0; t < T_; ++t) {
        const bf16* hr = hs + ((size_t)t*B_ + b)*H_ + u;
        const float h0 = (float)hr[0], h1 = (float)hr[1];
        const int o = t*H_ + u;
        a0 += h0*lW[o]         + h1*lW[o+1];
        a1 += h0*lW[24576+o]   + h1*lW[24576+o+1];
        a2 += h0*lW[49152+o]   + h1*lW[49152+o+1];
        a3 += h0*lW[73728+o]   + h1*lW[73728+o+1];
    }
    #pragma unroll
    for (int off = 32; off > 0; off >>= 1) {
        a0 += __shfl_down(a0, off, 64);
        a1 += __shfl_down(a1, off, 64);
        a2 += __shfl_down(a2, off, 64);
        a3 += __shfl_down(a3, off, 64);
    }
    __shared__ float red[4][4];
    const int wave = tid >> 6, lane = tid & 63;
    if (lane == 0) { red[0][wave]=a0; red[1][wave]=a1; red[2][wave]=a2; red[3][wave]=a3; }
    __syncthreads();
    if (tid < 4) {
        float s = red[tid][0]+red[tid][1]+red[tid][2]+red[tid][3] + lb[tid];
        out[b*4 + tid] = sigm(s);
    }
}

extern "C" void kernel_launch(void* const* d_in, const int* in_sizes, int n_in,
                              void* d_out, int out_size, void* d_ws, size_t ws_size,
                              hipStream_t stream) {
    const float* x   = (const float*)d_in[0];
    const float* ea  = (const float*)d_in[1];
    const float* cW  = (const float*)d_in[2];
    const float* cb  = (const float*)d_in[3];
    const float* gam = (const float*)d_in[4];
    const float* bet = (const float*)d_in[5];
    const float* Wih = (const float*)d_in[6];
    const float* Whh = (const float*)d_in[7];
    const float* bih = (const float*)d_in[8];
    const float* bhh = (const float*)d_in[9];
    const float* lW  = (const float*)d_in[10];
    const float* lb  = (const float*)d_in[11];
    const int*   ei  = (const int*)d_in[12];
    float* out = (float*)d_out;

    // Workspace (73.0 MB):
    // [bn_acc 40KB][Wp 2.75MB][X 15.7MB][big 54.5MB]
    // big phase 1: y_pre @0 (31.5MB), part @32MB (1.97MB)
    // big phase 2: c @0 (2MB), hA @2MB, hB @3MB, hs @4MB (50.3MB)
    char* ws = (char*)d_ws;
    float* bn_acc = (float*)ws;
    bf16*  Wp     = (bf16*)(ws + 40960);
    bf16*  X      = (bf16*)(ws + 2793472);
    char*  big    = ws + 18522112;
    float* y_pre  = (float*)big;
    float* part   = (float*)(big + 33554432);
    float* c_buf  = (float*)big;
    bf16*  hA     = (bf16*)(big + 2097152);
    bf16*  hB     = (bf16*)(big + 3145728);
    bf16*  hs     = (bf16*)(big + 4194304);

    (void)hipFuncSetAttribute((const void*)k_step,
                              hipFuncAttributeMaxDynamicSharedMemorySize, 65536);

    k_pack<<<5376, 256, 0, stream>>>(Wih, Whh, Wp);
    k_graph<<<NG_/4, 256, 0, stream>>>(x, ea, cW, cb, ei, y_pre, part);
    k_stats<<<B_, 64, 0, stream>>>(part, bn_acc);
    k_bn<<<NF_/256, 256, 0, stream>>>(y_pre, bn_acc, gam, bet, X);
    k_zero<<<768, 256, 0, stream>>>((float4*)c_buf, 196608);   // zero c_buf + hA
    for (int t = 0; t < T_; ++t) {
        const bf16* h_in  = (t & 1) ? hB : hA;
        bf16*       h_out = (t & 1) ? hA : hB;
        k_step<<<dim3(16, 32), 256, 65536, stream>>>(X + (size_t)t*B_*160, Wp, bih, bhh,
                                                     h_in, c_buf, h_out, hs + (size_t)t*B_*H_);
    }
    k_final<<<B_, 256, 0, stream>>>(hs, lW, lb, out);
}